// Round 13
// baseline (183.250 us; speedup 1.0000x reference)
//
#include <hip/hip_runtime.h>
#include <hip/hip_bf16.h>

#define H_NUM 16
#define D_DIM 64
#define S_LEN 2048
#define EMB   1024
#define M_TOT 4096   // B * S_LEN

typedef unsigned short u16;
typedef unsigned int   u32;
typedef __attribute__((ext_vector_type(8))) short short8;   // 8 bf16 in 4 VGPRs
typedef __attribute__((ext_vector_type(4))) float f32x4;    // MFMA C/D

__device__ __forceinline__ u32 f2bf_u(float f) {
    u32 u = __float_as_uint(f);
    return (u + 0x7fffu + ((u >> 16) & 1u)) >> 16;   // RNE, low 16 valid
}
__device__ __forceinline__ u32 pack2(float a, float b) {
    return f2bf_u(a) | (f2bf_u(b) << 16);
}
// 1-instr truncating bf16 pack: low16 = bf16(a) (RTZ), high16 = bf16(b) (RTZ)
__device__ __forceinline__ u32 pack2t(float a, float b) {
    return __builtin_amdgcn_perm(__float_as_uint(b), __float_as_uint(a),
                                 0x07060302u);
}
__device__ __forceinline__ uint4 pack8(float4 lo, float4 hi) {
    return make_uint4(pack2(lo.x, lo.y), pack2(lo.z, lo.w),
                      pack2(hi.x, hi.y), pack2(hi.z, hi.w));
}

// async global->LDS, 16B per lane; lds dest = wave-uniform base + lane*16
__device__ __forceinline__ void lds_dma16(const u16* g, u16* l) {
    __builtin_amdgcn_global_load_lds(
        (const __attribute__((address_space(1))) void*)g,
        (__attribute__((address_space(3))) void*)l, 16, 0, 0);
}

// ---------------------------------------------------------------------------
// Kernel 0: cast f32 inputs -> bf16 ws copies; seg 5 builds RoPE cos/sin table
// ---------------------------------------------------------------------------
__global__ __launch_bounds__(256) void cast_kernel(
    const float* __restrict__ x,  const float* __restrict__ Wq,
    const float* __restrict__ Wk, const float* __restrict__ Wv,
    const float* __restrict__ Wo, u16* __restrict__ ws, float2* __restrict__ tab)
{
    const int seg = blockIdx.y;
    if (seg == 5) {
        const int idx = blockIdx.x * 256 + threadIdx.x;
        if (idx < S_LEN * 32) {
            const int s = idx >> 5, d = idx & 31;
            const float ang = (float)s * __expf(-(float)d * 0.28782313662425573f);
            tab[idx] = make_float2(cosf(ang), sinf(ang));
        }
        return;
    }
    const float* src = (seg == 0) ? x : (seg == 1) ? Wq : (seg == 2) ? Wk
                     : (seg == 3) ? Wv : Wo;
    u16* dst = (seg == 0) ? ws : ws + (3 + seg) * 1048576;   // xb@0, W*@4M..7M
    const int n = (seg == 0) ? 4194304 : 1048576;
    const int idx = (blockIdx.x * 256 + threadIdx.x) * 8;
    if (idx < n) {
        float4 lo = *(const float4*)(src + idx);
        float4 hi = *(const float4*)(src + idx + 4);
        *(uint4*)(dst + idx) = pack8(lo, hi);
    }
}

// ---------------------------------------------------------------------------
// Kernel A: GEMM, 64x128 tiles; grid (64,24) = 1536 blocks = 6/CU, LDS 24 KB.
// x = m-block (XCD=m%8), y = z*8 + n.
// w==2 (V) stores V^T [B,H,D,S] tau-permuted (tau(p)=((p&3)<<4)|(p>>2)).
// ---------------------------------------------------------------------------
__global__ __launch_bounds__(256) void qkv_rope_kernel(
    const u16* __restrict__ xb, const u16* __restrict__ wb,
    const float2* __restrict__ tab,
    u16* __restrict__ qo, u16* __restrict__ ko, u16* __restrict__ vo)
{
    const int w  = blockIdx.y >> 3;         // 0..2
    const int nb = blockIdx.y & 7;          // 0..7
    const u16* W = wb + w * 1048576;

    __shared__ __align__(16) u16 smem[12288];   // As 4K + Bs 8K u16; Ep 64x132
    u16* As = smem;
    u16* Bs = smem + 64 * 64;
    u16 (*Ep)[132] = (u16(*)[132])smem;

    const int tid   = threadIdx.x;
    const int lane  = tid & 63;
    const int wid   = tid >> 6;
    const int waveM = wid >> 1;          // 0..1 (32-row slice)
    const int waveN = wid & 1;           // 0..1 (64-col slice)
    const int col16 = lane & 15;
    const int quad  = lane >> 4;

    const int m0 = blockIdx.x * 64;
    const int n0 = nb * 128;

    f32x4 acc[2][4];
    const f32x4 zero4 = {0.f, 0.f, 0.f, 0.f};
#pragma unroll
    for (int i = 0; i < 2; i++)
#pragma unroll
        for (int j = 0; j < 4; j++) acc[i][j] = zero4;

    const int drow = tid >> 3;          // 0..31
    const int dpos = tid & 7;
    const u16* Ag = xb + (size_t)m0 * EMB;
    const u16* Bg = W  + (size_t)n0 * EMB;

    for (int k0 = 0; k0 < EMB; k0 += 64) {
        __syncthreads();
#pragma unroll
        for (int j = 0; j < 2; j++) {
            const int rl = j * 32 + drow;
            const int cg = dpos ^ (rl & 7);
            lds_dma16(Ag + (size_t)rl * EMB + k0 + cg * 8,
                      As + (j * 32 + wid * 8) * 64);
        }
#pragma unroll
        for (int j = 0; j < 4; j++) {
            const int rl = j * 32 + drow;
            const int cg = dpos ^ (rl & 7);
            lds_dma16(Bg + (size_t)rl * EMB + k0 + cg * 8,
                      Bs + (j * 32 + wid * 8) * 64);
        }
        __syncthreads();

        short8 af[2][2], bf[4][2];
#pragma unroll
        for (int mt = 0; mt < 2; mt++) {
            const int r = waveM * 32 + mt * 16 + col16;
#pragma unroll
            for (int ks = 0; ks < 2; ks++) {
                const int p = (ks * 4 + quad) ^ (r & 7);
                af[mt][ks] = *(const short8*)(As + r * 64 + p * 8);
            }
        }
#pragma unroll
        for (int nt = 0; nt < 4; nt++) {
            const int r = waveN * 64 + nt * 16 + col16;
#pragma unroll
            for (int ks = 0; ks < 2; ks++) {
                const int p = (ks * 4 + quad) ^ (r & 7);
                bf[nt][ks] = *(const short8*)(Bs + r * 64 + p * 8);
            }
        }
#pragma unroll
        for (int ks = 0; ks < 2; ks++)
#pragma unroll
            for (int mt = 0; mt < 2; mt++)
#pragma unroll
                for (int nt = 0; nt < 4; nt++)
                    acc[mt][nt] = __builtin_amdgcn_mfma_f32_16x16x32_bf16(
                        af[mt][ks], bf[nt][ks], acc[mt][nt], 0, 0, 0);
    }

    // ---- epilogue: RoPE (table) + LDS round trip + 16B coalesced stores ----
    __syncthreads();
#pragma unroll
    for (int mt = 0; mt < 2; mt++) {
#pragma unroll
        for (int r = 0; r < 4; r++) {
            const int m_local = waveM * 32 + mt * 16 + quad * 4 + r;
            const int s = (m0 + m_local) & 2047;
            if (w == 2) {
#pragma unroll
                for (int nt = 0; nt < 4; nt++)
                    Ep[m_local][waveN * 64 + nt * 16 + col16] =
                        (u16)f2bf_u(acc[mt][nt][r]);
            } else {
#pragma unroll
                for (int nt = 0; nt < 2; nt++) {
                    const int d = nt * 16 + col16;          // [0,32)
                    const float2 cs = tab[s * 32 + d];
                    const float lo = acc[mt][nt][r];
                    const float hi = acc[mt][nt + 2][r];
                    Ep[m_local][waveN * 64 + d]      = (u16)f2bf_u(lo * cs.x - hi * cs.y);
                    Ep[m_local][waveN * 64 + d + 32] = (u16)f2bf_u(hi * cs.x + lo * cs.y);
                }
            }
        }
    }
    __syncthreads();

    const int b = m0 >> 11;
    if (w != 2) {
        u16* out = (w == 0) ? qo : ko;
#pragma unroll
        for (int j = 0; j < 4; j++) {
            const int g = j * 256 + tid;        // [0,1024): 2 heads x 64 s x 8
            const int head_local = g >> 9;
            const int sl  = (g >> 3) & 63;
            const int cir = g & 7;
            uint4 val = *(const uint4*)(&Ep[sl][head_local * 64 + cir * 8]);
            const int h = (n0 >> 6) + head_local;
            const size_t base = (((size_t)(b * H_NUM + h)) * S_LEN + (m0 & 2047)) * 64;
            *(uint4*)(out + base + (size_t)(g & 511) * 8) = val;
        }
    } else {
        // V^T store: vo[((b*16+h)*64+d)*2048 + s]; one tau 64-block (s-span 64)
        const int s0 = m0 & 2047;
#pragma unroll
        for (int j = 0; j < 4; j++) {
            const int g = j * 256 + tid;        // [0,1024): d_all(128) x sc(8)
            const int d_all = g >> 3;           // 0..127
            const int sc = g & 7;               // s-chunk of 8
            u32 wv[4];
#pragma unroll
            for (int hw = 0; hw < 4; hw++) {
                const int p0 = sc * 8 + hw * 2;
                const int r0 = ((p0 & 3) << 4) | (p0 >> 2);
                const int p1 = p0 + 1;
                const int r1 = ((p1 & 3) << 4) | (p1 >> 2);
                wv[hw] = (u32)Ep[r0][d_all] | ((u32)Ep[r1][d_all] << 16);
            }
            const int h = (n0 >> 6) + (d_all >> 6);
            const int d = d_all & 63;
            *(uint4*)(vo + ((size_t)(b * H_NUM + h) * 64 + d) * 2048 + s0 + sc * 8) =
                make_uint4(wv[0], wv[1], wv[2], wv[3]);
        }
    }
}

// ---------------------------------------------------------------------------
// Kernel B: causal flash attention. R13: 32-row q-tiles, 128-thread blocks,
// grid (32, 64) = 2048 blocks = 8/CU (tail-filling). Wave owns 16 rows.
// Mask only on last kt tile. P/O packs via v_perm (truncating bf16).
// ---------------------------------------------------------------------------
__global__ __launch_bounds__(128) void attn_kernel(
    const u16* __restrict__ q, const u16* __restrict__ k,
    const u16* __restrict__ v, u16* __restrict__ ctx)
{
    __shared__ __align__(16) u16 QP[32 * 64];     // Q staging, then per-wave P/O
    __shared__ __align__(16) u16 Ks[64 * 64];
    __shared__ __align__(16) u16 VTs[64 * 64];

    const int tid   = threadIdx.x;
    const int lane  = tid & 63;
    const int wid   = tid >> 6;          // 0..1
    const int col16 = lane & 15;
    const int quad  = lane >> 4;

    const int bh    = blockIdx.x;
    const int qb    = 63 - blockIdx.y;   // heavy blocks dispatch first
    const int qBase = qb * 32;
    const size_t bhOff = (size_t)bh * S_LEN * D_DIM;   // same for V^T (64*2048)

    const int lrow8 = lane >> 3;         // 0..7
    const int lpos  = lane & 7;

    // stage Q tile (32x64): 2 calls x 2 waves x 8 rows
#pragma unroll
    for (int j = 0; j < 2; j++) {
        const int rl = j * 16 + wid * 8 + lrow8;
        const int cg = lpos ^ (rl & 7);
        lds_dma16(q + bhOff + (size_t)(qBase + rl) * 64 + cg * 8,
                  QP + (j * 16 + wid * 8) * 64);
    }
    __syncthreads();

    short8 qf[2];
    {
        const int rq = wid * 16 + col16;
#pragma unroll
        for (int ks = 0; ks < 2; ks++) {
            const int c = (ks * 4 + quad) ^ (rq & 7);
            qf[ks] = *(const short8*)(QP + rq * 64 + c * 8);
        }
    }

    f32x4 O[4];
    const f32x4 zero4 = {0.f, 0.f, 0.f, 0.f};
#pragma unroll
    for (int j = 0; j < 4; j++) O[j] = zero4;
    float lrun[4] = {0.f, 0.f, 0.f, 0.f};

    const float K2 = 0.18033688011112042f;   // 0.125 * log2(e)
    const int ktEnd = (qBase + 31) >> 6;

    for (int kt = 0; kt <= ktEnd; kt++) {
        __syncthreads();
        // stage K (64x64) and V^T (64x64): 4 calls x 2 waves x 8 rows each
#pragma unroll
        for (int j = 0; j < 4; j++) {
            const int rl = j * 16 + wid * 8 + lrow8;
            const int cg = lpos ^ (rl & 7);
            lds_dma16(k + bhOff + (size_t)(kt * 64 + rl) * 64 + cg * 8,
                      Ks + (j * 16 + wid * 8) * 64);
        }
#pragma unroll
        for (int j = 0; j < 4; j++) {
            const int rl = j * 16 + wid * 8 + lrow8;
            const int cg = lpos ^ (rl & 7);
            lds_dma16(v + bhOff + (size_t)rl * 2048 + kt * 64 + cg * 8,
                      VTs + (j * 16 + wid * 8) * 64);
        }
        __syncthreads();

        f32x4 sc[4];
#pragma unroll
        for (int nt = 0; nt < 4; nt++) sc[nt] = zero4;
#pragma unroll
        for (int ks = 0; ks < 2; ks++) {
            short8 kf[4];
#pragma unroll
            for (int nt = 0; nt < 4; nt++) {
                const int rk = nt * 16 + col16;
                const int c = (ks * 4 + quad) ^ (rk & 7);
                kf[nt] = *(const short8*)(Ks + rk * 64 + c * 8);
            }
#pragma unroll
            for (int nt = 0; nt < 4; nt++)
                sc[nt] = __builtin_amdgcn_mfma_f32_16x16x32_bf16(
                    qf[ks], kf[nt], sc[nt], 0, 0, 0);
        }

        // fixed-max log2-domain softmax; mask only on the last tile
        if (kt == ktEnd) {
#pragma unroll
            for (int r = 0; r < 4; r++) {
                const int qg = qBase + wid * 16 + quad * 4 + r;
                float lsum = 0.f;
#pragma unroll
                for (int nt = 0; nt < 4; nt++) {
                    const int kg = kt * 64 + nt * 16 + col16;
                    float sv = fmaf(sc[nt][r], K2, -16.0f);
                    if (kg > qg) sv = -INFINITY;
                    const float p = exp2f(sv);
                    sc[nt][r] = p;
                    lsum += p;
                }
                lrun[r] += lsum;
            }
        } else {
#pragma unroll
            for (int r = 0; r < 4; r++) {
                float lsum = 0.f;
#pragma unroll
                for (int nt = 0; nt < 4; nt++) {
                    const float p = exp2f(fmaf(sc[nt][r], K2, -16.0f));
                    sc[nt][r] = p;
                    lsum += p;
                }
                lrun[r] += lsum;
            }
        }

        // P -> wave-private LDS rows, b64 at pos=col16*4+nt (tau-order)
#pragma unroll
        for (int r = 0; r < 4; r++) {
            const int ml = quad * 4 + r;
            const u32 lo = pack2t(sc[0][r], sc[1][r]);
            const u32 hi = pack2t(sc[2][r], sc[3][r]);
            *(uint2*)(QP + (wid * 16 + ml) * 64 +
                      (((col16 >> 1) ^ (ml & 7)) * 8 + (col16 & 1) * 4)) =
                make_uint2(lo, hi);
        }

#pragma unroll
        for (int ks = 0; ks < 2; ks++) {
            short8 pf, vf[4];
            {
                const int c = (ks * 4 + quad) ^ (col16 & 7);
                pf = *(const short8*)(QP + (wid * 16 + col16) * 64 + c * 8);
            }
#pragma unroll
            for (int dt = 0; dt < 4; dt++) {
                const int d = dt * 16 + col16;
                const int c = (ks * 4 + quad) ^ (d & 7);
                vf[dt] = *(const short8*)(VTs + d * 64 + c * 8);
            }
#pragma unroll
            for (int dt = 0; dt < 4; dt++)
                O[dt] = __builtin_amdgcn_mfma_f32_16x16x32_bf16(
                    pf, vf[dt], O[dt], 0, 0, 0);
        }
    }

    // row-sum reduction over the 16 col16 lanes (once)
#pragma unroll
    for (int r = 0; r < 4; r++) {
#pragma unroll
        for (int o = 1; o < 16; o <<= 1)
            lrun[r] += __shfl_xor(lrun[r], o);
    }

    // O epilogue: b64 pos-layout (pos = col16*4 + dt), then gather to ctx
    const int b = bh >> 4, h = bh & 15;
#pragma unroll
    for (int r = 0; r < 4; r++) {
        const int ml = quad * 4 + r;
        const float inv = 1.0f / lrun[r];
        const u32 lo = pack2t(O[0][r] * inv, O[1][r] * inv);
        const u32 hi = pack2t(O[2][r] * inv, O[3][r] * inv);
        *(uint2*)(QP + (wid * 16 + ml) * 64 +
                  (((col16 >> 1) ^ (ml & 7)) * 8 + (col16 & 1) * 4)) =
            make_uint2(lo, hi);
    }
#pragma unroll
    for (int j = 0; j < 2; j++) {
        const int g  = j * 64 + lane;       // 128 chunks: 16 rows x 8 d-chunks
        const int sl = g >> 3;
        const int cir = g & 7;
        u32 wv[4];
#pragma unroll
        for (int hw = 0; hw < 4; hw++) {
            const int d0 = cir * 8 + hw * 2;
            const int p0 = ((d0 & 15) << 2) | (d0 >> 4);
            const int d1 = d0 + 1;
            const int p1 = ((d1 & 15) << 2) | (d1 >> 4);
            const u16 v0 = QP[(wid * 16 + sl) * 64 + ((p0 >> 3) ^ (sl & 7)) * 8 + (p0 & 7)];
            const u16 v1 = QP[(wid * 16 + sl) * 64 + ((p1 >> 3) ^ (sl & 7)) * 8 + (p1 & 7)];
            wv[hw] = (u32)v0 | ((u32)v1 << 16);
        }
        const size_t rowbase =
            ((size_t)b * S_LEN + qBase + wid * 16 + sl) * EMB + h * 64;
        *(uint4*)(ctx + rowbase + cir * 8) = make_uint4(wv[0], wv[1], wv[2], wv[3]);
    }
}

// ---------------------------------------------------------------------------
// Kernel C: out(f32) = ctx * Wo^T. 64x128 tiles, grid (64, 8) = 512 blocks.
// ---------------------------------------------------------------------------
__global__ __launch_bounds__(256) void proj_kernel(
    const u16* __restrict__ X, const u16* __restrict__ W, float* __restrict__ out)
{
    __shared__ __align__(16) u16 smem[12288];   // As 64x64 + Bs 128x64
    u16* As = smem;
    u16* Bs = smem + 64 * 64;

    const int tid   = threadIdx.x;
    const int lane  = tid & 63;
    const int wid   = tid >> 6;
    const int waveM = wid >> 1;          // 0..1
    const int waveN = wid & 1;
    const int col16 = lane & 15;
    const int quad  = lane >> 4;

    const int m0 = blockIdx.x * 64;
    const int n0 = blockIdx.y * 128;

    f32x4 acc[4][2];   // [nt][mt] (operand-swapped)
    const f32x4 zero4 = {0.f, 0.f, 0.f, 0.f};
#pragma unroll
    for (int i = 0; i < 4; i++)
#pragma unroll
        for (int j = 0; j < 2; j++) acc[i][j] = zero4;

    const int drow = tid >> 3;
    const int dpos = tid & 7;
    const u16* Ag = X + (size_t)m0 * EMB;
    const u16* Bg = W + (size_t)n0 * EMB;

    for (int k0 = 0; k0 < EMB; k0 += 64) {
        __syncthreads();
#pragma unroll
        for (int j = 0; j < 2; j++) {
            const int rl = j * 32 + drow;
            const int cg = dpos ^ (rl & 7);
            lds_dma16(Ag + (size_t)rl * EMB + k0 + cg * 8,
                      As + (j * 32 + wid * 8) * 64);
        }
#pragma unroll
        for (int j = 0; j < 4; j++) {
            const int rl = j * 32 + drow;
            const int cg = dpos ^ (rl & 7);
            lds_dma16(Bg + (size_t)rl * EMB + k0 + cg * 8,
                      Bs + (j * 32 + wid * 8) * 64);
        }
        __syncthreads();

        short8 af[2][2], bf[4][2];
#pragma unroll
        for (int mt = 0; mt < 2; mt++) {
            const int r = waveM * 32 + mt * 16 + col16;
#pragma unroll
            for (int ks = 0; ks < 2; ks++) {
                const int p = (ks * 4 + quad) ^ (r & 7);
                af[mt][ks] = *(const short8*)(As + r * 64 + p * 8);
            }
        }
#pragma unroll
        for (int nt = 0; nt < 4; nt++) {
            const int r = waveN * 64 + nt * 16 + col16;
#pragma unroll
            for (int ks = 0; ks < 2; ks++) {
                const int p = (ks * 4 + quad) ^ (r & 7);
                bf[nt][ks] = *(const short8*)(Bs + r * 64 + p * 8);
            }
        }
#pragma unroll
        for (int ks = 0; ks < 2; ks++)
#pragma unroll
            for (int nt = 0; nt < 4; nt++)
#pragma unroll
                for (int mt = 0; mt < 2; mt++)
                    acc[nt][mt] = __builtin_amdgcn_mfma_f32_16x16x32_bf16(
                        bf[nt][ks], af[mt][ks], acc[nt][mt], 0, 0, 0);
    }

#pragma unroll
    for (int nt = 0; nt < 4; nt++)
#pragma unroll
        for (int mt = 0; mt < 2; mt++) {
            const int m_g = m0 + waveM * 32 + mt * 16 + col16;
            const int n_g = n0 + waveN * 64 + nt * 16 + quad * 4;
            *(f32x4*)(out + (size_t)m_g * EMB + n_g) = acc[nt][mt];
        }
}

// ---------------------------------------------------------------------------
extern "C" void kernel_launch(void* const* d_in, const int* in_sizes, int n_in,
                              void* d_out, int out_size, void* d_ws, size_t ws_size,
                              hipStream_t stream)
{
    const float* x  = (const float*)d_in[0];
    const float* Wq = (const float*)d_in[1];
    const float* Wk = (const float*)d_in[2];
    const float* Wv = (const float*)d_in[3];
    const float* Wo = (const float*)d_in[4];

    u16* ws = (u16*)d_ws;
    u16* xb  = ws;
    u16* wb  = ws + 4194304;            // wq,wk,wv contiguous
    u16* wob = ws + 7340032;
    u16* q   = ws + 8388608;
    u16* k   = ws + 12582912;
    u16* v   = ws + 16777216;           // V^T [B,H,D,S], tau-ordered
    u16* ctx = ws + 20971520;
    float2* tab = (float2*)(ws + 25165824);   // 2048x32 float2 = 512 KB

    cast_kernel<<<dim3(2048, 6), 256, 0, stream>>>(x, Wq, Wk, Wv, Wo, ws, tab);
    qkv_rope_kernel<<<dim3(64, 24), 256, 0, stream>>>(xb, wb, tab, q, k, v);
    attn_kernel<<<dim3(32, 64), 128, 0, stream>>>(q, k, v, ctx);
    proj_kernel<<<dim3(64, 8), 256, 0, stream>>>(ctx, wob, (float*)d_out);
}

// Round 14
// 175.019 us; speedup vs baseline: 1.0470x; 1.0470x over previous
//
#include <hip/hip_runtime.h>
#include <hip/hip_bf16.h>

#define H_NUM 16
#define D_DIM 64
#define S_LEN 2048
#define EMB   1024
#define M_TOT 4096   // B * S_LEN

typedef unsigned short u16;
typedef unsigned int   u32;
typedef __attribute__((ext_vector_type(8))) short short8;   // 8 bf16 in 4 VGPRs
typedef __attribute__((ext_vector_type(4))) float f32x4;    // MFMA C/D

__device__ __forceinline__ u32 f2bf_u(float f) {
    u32 u = __float_as_uint(f);
    return (u + 0x7fffu + ((u >> 16) & 1u)) >> 16;   // RNE, low 16 valid
}
__device__ __forceinline__ u32 pack2(float a, float b) {
    return f2bf_u(a) | (f2bf_u(b) << 16);
}
// 1-instr truncating bf16 pack: low16 = bf16(a) (RTZ), high16 = bf16(b) (RTZ)
__device__ __forceinline__ u32 pack2t(float a, float b) {
    return __builtin_amdgcn_perm(__float_as_uint(b), __float_as_uint(a),
                                 0x07060302u);
}
__device__ __forceinline__ uint4 pack8(float4 lo, float4 hi) {
    return make_uint4(pack2(lo.x, lo.y), pack2(lo.z, lo.w),
                      pack2(hi.x, hi.y), pack2(hi.z, hi.w));
}

// async global->LDS, 16B per lane; lds dest = wave-uniform base + lane*16
__device__ __forceinline__ void lds_dma16(const u16* g, u16* l) {
    __builtin_amdgcn_global_load_lds(
        (const __attribute__((address_space(1))) void*)g,
        (__attribute__((address_space(3))) void*)l, 16, 0, 0);
}

// ---------------------------------------------------------------------------
// Kernel 0: cast f32 inputs -> bf16 ws copies; seg 5 builds RoPE cos/sin table
// ---------------------------------------------------------------------------
__global__ __launch_bounds__(256) void cast_kernel(
    const float* __restrict__ x,  const float* __restrict__ Wq,
    const float* __restrict__ Wk, const float* __restrict__ Wv,
    const float* __restrict__ Wo, u16* __restrict__ ws, float2* __restrict__ tab)
{
    const int seg = blockIdx.y;
    if (seg == 5) {
        const int idx = blockIdx.x * 256 + threadIdx.x;
        if (idx < S_LEN * 32) {
            const int s = idx >> 5, d = idx & 31;
            const float ang = (float)s * __expf(-(float)d * 0.28782313662425573f);
            tab[idx] = make_float2(cosf(ang), sinf(ang));
        }
        return;
    }
    const float* src = (seg == 0) ? x : (seg == 1) ? Wq : (seg == 2) ? Wk
                     : (seg == 3) ? Wv : Wo;
    u16* dst = (seg == 0) ? ws : ws + (3 + seg) * 1048576;   // xb@0, W*@4M..7M
    const int n = (seg == 0) ? 4194304 : 1048576;
    const int idx = (blockIdx.x * 256 + threadIdx.x) * 8;
    if (idx < n) {
        float4 lo = *(const float4*)(src + idx);
        float4 hi = *(const float4*)(src + idx + 4);
        *(uint4*)(dst + idx) = pack8(lo, hi);
    }
}

// ---------------------------------------------------------------------------
// Kernel A: GEMM, 64x128 tiles; grid (64,24) = 1536 blocks = 6/CU, LDS 24 KB.
// x = m-block (XCD=m%8), y = z*8 + n.
// w==2 (V) stores V^T [B,H,D,S] tau-permuted (tau(p)=((p&3)<<4)|(p>>2)).
// ---------------------------------------------------------------------------
__global__ __launch_bounds__(256) void qkv_rope_kernel(
    const u16* __restrict__ xb, const u16* __restrict__ wb,
    const float2* __restrict__ tab,
    u16* __restrict__ qo, u16* __restrict__ ko, u16* __restrict__ vo)
{
    const int w  = blockIdx.y >> 3;         // 0..2
    const int nb = blockIdx.y & 7;          // 0..7
    const u16* W = wb + w * 1048576;

    __shared__ __align__(16) u16 smem[12288];   // As 4K + Bs 8K u16; Ep 64x132
    u16* As = smem;
    u16* Bs = smem + 64 * 64;
    u16 (*Ep)[132] = (u16(*)[132])smem;

    const int tid   = threadIdx.x;
    const int lane  = tid & 63;
    const int wid   = tid >> 6;
    const int waveM = wid >> 1;          // 0..1 (32-row slice)
    const int waveN = wid & 1;           // 0..1 (64-col slice)
    const int col16 = lane & 15;
    const int quad  = lane >> 4;

    const int m0 = blockIdx.x * 64;
    const int n0 = nb * 128;

    f32x4 acc[2][4];
    const f32x4 zero4 = {0.f, 0.f, 0.f, 0.f};
#pragma unroll
    for (int i = 0; i < 2; i++)
#pragma unroll
        for (int j = 0; j < 4; j++) acc[i][j] = zero4;

    const int drow = tid >> 3;          // 0..31
    const int dpos = tid & 7;
    const u16* Ag = xb + (size_t)m0 * EMB;
    const u16* Bg = W  + (size_t)n0 * EMB;

    for (int k0 = 0; k0 < EMB; k0 += 64) {
        __syncthreads();
#pragma unroll
        for (int j = 0; j < 2; j++) {
            const int rl = j * 32 + drow;
            const int cg = dpos ^ (rl & 7);
            lds_dma16(Ag + (size_t)rl * EMB + k0 + cg * 8,
                      As + (j * 32 + wid * 8) * 64);
        }
#pragma unroll
        for (int j = 0; j < 4; j++) {
            const int rl = j * 32 + drow;
            const int cg = dpos ^ (rl & 7);
            lds_dma16(Bg + (size_t)rl * EMB + k0 + cg * 8,
                      Bs + (j * 32 + wid * 8) * 64);
        }
        __syncthreads();

        short8 af[2][2], bf[4][2];
#pragma unroll
        for (int mt = 0; mt < 2; mt++) {
            const int r = waveM * 32 + mt * 16 + col16;
#pragma unroll
            for (int ks = 0; ks < 2; ks++) {
                const int p = (ks * 4 + quad) ^ (r & 7);
                af[mt][ks] = *(const short8*)(As + r * 64 + p * 8);
            }
        }
#pragma unroll
        for (int nt = 0; nt < 4; nt++) {
            const int r = waveN * 64 + nt * 16 + col16;
#pragma unroll
            for (int ks = 0; ks < 2; ks++) {
                const int p = (ks * 4 + quad) ^ (r & 7);
                bf[nt][ks] = *(const short8*)(Bs + r * 64 + p * 8);
            }
        }
#pragma unroll
        for (int ks = 0; ks < 2; ks++)
#pragma unroll
            for (int mt = 0; mt < 2; mt++)
#pragma unroll
                for (int nt = 0; nt < 4; nt++)
                    acc[mt][nt] = __builtin_amdgcn_mfma_f32_16x16x32_bf16(
                        af[mt][ks], bf[nt][ks], acc[mt][nt], 0, 0, 0);
    }

    // ---- epilogue: RoPE (table) + LDS round trip + 16B coalesced stores ----
    __syncthreads();
#pragma unroll
    for (int mt = 0; mt < 2; mt++) {
#pragma unroll
        for (int r = 0; r < 4; r++) {
            const int m_local = waveM * 32 + mt * 16 + quad * 4 + r;
            const int s = (m0 + m_local) & 2047;
            if (w == 2) {
#pragma unroll
                for (int nt = 0; nt < 4; nt++)
                    Ep[m_local][waveN * 64 + nt * 16 + col16] =
                        (u16)f2bf_u(acc[mt][nt][r]);
            } else {
#pragma unroll
                for (int nt = 0; nt < 2; nt++) {
                    const int d = nt * 16 + col16;          // [0,32)
                    const float2 cs = tab[s * 32 + d];
                    const float lo = acc[mt][nt][r];
                    const float hi = acc[mt][nt + 2][r];
                    Ep[m_local][waveN * 64 + d]      = (u16)f2bf_u(lo * cs.x - hi * cs.y);
                    Ep[m_local][waveN * 64 + d + 32] = (u16)f2bf_u(hi * cs.x + lo * cs.y);
                }
            }
        }
    }
    __syncthreads();

    const int b = m0 >> 11;
    if (w != 2) {
        u16* out = (w == 0) ? qo : ko;
#pragma unroll
        for (int j = 0; j < 4; j++) {
            const int g = j * 256 + tid;        // [0,1024): 2 heads x 64 s x 8
            const int head_local = g >> 9;
            const int sl  = (g >> 3) & 63;
            const int cir = g & 7;
            uint4 val = *(const uint4*)(&Ep[sl][head_local * 64 + cir * 8]);
            const int h = (n0 >> 6) + head_local;
            const size_t base = (((size_t)(b * H_NUM + h)) * S_LEN + (m0 & 2047)) * 64;
            *(uint4*)(out + base + (size_t)(g & 511) * 8) = val;
        }
    } else {
        // V^T store: vo[((b*16+h)*64+d)*2048 + s]; one tau 64-block (s-span 64)
        const int s0 = m0 & 2047;
#pragma unroll
        for (int j = 0; j < 4; j++) {
            const int g = j * 256 + tid;        // [0,1024): d_all(128) x sc(8)
            const int d_all = g >> 3;           // 0..127
            const int sc = g & 7;               // s-chunk of 8
            u32 wv[4];
#pragma unroll
            for (int hw = 0; hw < 4; hw++) {
                const int p0 = sc * 8 + hw * 2;
                const int r0 = ((p0 & 3) << 4) | (p0 >> 2);
                const int p1 = p0 + 1;
                const int r1 = ((p1 & 3) << 4) | (p1 >> 2);
                wv[hw] = (u32)Ep[r0][d_all] | ((u32)Ep[r1][d_all] << 16);
            }
            const int h = (n0 >> 6) + (d_all >> 6);
            const int d = d_all & 63;
            *(uint4*)(vo + ((size_t)(b * H_NUM + h) * 64 + d) * 2048 + s0 + sc * 8) =
                make_uint4(wv[0], wv[1], wv[2], wv[3]);
        }
    }
}

// ---------------------------------------------------------------------------
// Kernel B: causal flash attention. R14 = R12 structure (64-row q-tiles,
// 256 threads, grid (32,32) = 4/CU) + pack2t (v_perm truncating bf16 pack)
// for P/O. Mask only on diagonal tile. Heavy blocks dispatch first.
// ---------------------------------------------------------------------------
__global__ __launch_bounds__(256) void attn_kernel(
    const u16* __restrict__ q, const u16* __restrict__ k,
    const u16* __restrict__ v, u16* __restrict__ ctx)
{
    __shared__ __align__(16) u16 QP[64 * 64];     // Q staging, then per-wave P/O
    __shared__ __align__(16) u16 Ks[64 * 64];
    __shared__ __align__(16) u16 VTs[64 * 64];

    const int tid   = threadIdx.x;
    const int lane  = tid & 63;
    const int wid   = tid >> 6;
    const int col16 = lane & 15;
    const int quad  = lane >> 4;

    const int bh    = blockIdx.x;
    const int qb    = 31 - blockIdx.y;     // heavy blocks dispatch first
    const int qBase = qb * 64;
    const size_t bhOff = (size_t)bh * S_LEN * D_DIM;   // same for V^T (64*2048)

    const int drow = tid >> 3;          // 0..31
    const int dpos = tid & 7;

    // stage Q tile (64x64) via dma, chunk-swizzled
#pragma unroll
    for (int j = 0; j < 2; j++) {
        const int rl = j * 32 + drow;
        const int cg = dpos ^ (rl & 7);
        lds_dma16(q + bhOff + (size_t)(qBase + rl) * 64 + cg * 8,
                  QP + (j * 32 + wid * 8) * 64);
    }
    __syncthreads();

    short8 qf[2];
    {
        const int rq = wid * 16 + col16;
#pragma unroll
        for (int ks = 0; ks < 2; ks++) {
            const int c = (ks * 4 + quad) ^ (rq & 7);
            qf[ks] = *(const short8*)(QP + rq * 64 + c * 8);
        }
    }

    f32x4 O[4];
    const f32x4 zero4 = {0.f, 0.f, 0.f, 0.f};
#pragma unroll
    for (int j = 0; j < 4; j++) O[j] = zero4;
    float lrun[4] = {0.f, 0.f, 0.f, 0.f};

    const float K2 = 0.18033688011112042f;   // 0.125 * log2(e)

    for (int kt = 0; kt <= qb; kt++) {
        __syncthreads();
#pragma unroll
        for (int j = 0; j < 2; j++) {
            const int rl = j * 32 + drow;
            const int cg = dpos ^ (rl & 7);
            lds_dma16(k + bhOff + (size_t)(kt * 64 + rl) * 64 + cg * 8,
                      Ks + (j * 32 + wid * 8) * 64);
        }
#pragma unroll
        for (int j = 0; j < 2; j++) {
            const int rl = j * 32 + drow;
            const int cg = dpos ^ (rl & 7);
            lds_dma16(v + bhOff + (size_t)rl * 2048 + kt * 64 + cg * 8,
                      VTs + (j * 32 + wid * 8) * 64);
        }
        __syncthreads();

        f32x4 sc[4];
#pragma unroll
        for (int nt = 0; nt < 4; nt++) sc[nt] = zero4;
#pragma unroll
        for (int ks = 0; ks < 2; ks++) {
            short8 kf[4];
#pragma unroll
            for (int nt = 0; nt < 4; nt++) {
                const int rk = nt * 16 + col16;
                const int c = (ks * 4 + quad) ^ (rk & 7);
                kf[nt] = *(const short8*)(Ks + rk * 64 + c * 8);
            }
#pragma unroll
            for (int nt = 0; nt < 4; nt++)
                sc[nt] = __builtin_amdgcn_mfma_f32_16x16x32_bf16(
                    qf[ks], kf[nt], sc[nt], 0, 0, 0);
        }

        // fixed-max log2-domain softmax; mask only on the diagonal tile
        if (kt == qb) {
#pragma unroll
            for (int r = 0; r < 4; r++) {
                const int qg = qBase + wid * 16 + quad * 4 + r;
                float lsum = 0.f;
#pragma unroll
                for (int nt = 0; nt < 4; nt++) {
                    const int kg = kt * 64 + nt * 16 + col16;
                    float sv = fmaf(sc[nt][r], K2, -16.0f);
                    if (kg > qg) sv = -INFINITY;
                    const float p = exp2f(sv);
                    sc[nt][r] = p;
                    lsum += p;
                }
                lrun[r] += lsum;
            }
        } else {
#pragma unroll
            for (int r = 0; r < 4; r++) {
                float lsum = 0.f;
#pragma unroll
                for (int nt = 0; nt < 4; nt++) {
                    const float p = exp2f(fmaf(sc[nt][r], K2, -16.0f));
                    sc[nt][r] = p;
                    lsum += p;
                }
                lrun[r] += lsum;
            }
        }

        // P -> wave-private LDS rows, b64 at pos=col16*4+nt (tau-order)
#pragma unroll
        for (int r = 0; r < 4; r++) {
            const int ml = quad * 4 + r;
            const u32 lo = pack2t(sc[0][r], sc[1][r]);
            const u32 hi = pack2t(sc[2][r], sc[3][r]);
            *(uint2*)(QP + (wid * 16 + ml) * 64 +
                      (((col16 >> 1) ^ (ml & 7)) * 8 + (col16 & 1) * 4)) =
                make_uint2(lo, hi);
        }

#pragma unroll
        for (int ks = 0; ks < 2; ks++) {
            short8 pf, vf[4];
            {
                const int c = (ks * 4 + quad) ^ (col16 & 7);
                pf = *(const short8*)(QP + (wid * 16 + col16) * 64 + c * 8);
            }
#pragma unroll
            for (int dt = 0; dt < 4; dt++) {
                const int d = dt * 16 + col16;
                const int c = (ks * 4 + quad) ^ (d & 7);
                vf[dt] = *(const short8*)(VTs + d * 64 + c * 8);
            }
#pragma unroll
            for (int dt = 0; dt < 4; dt++)
                O[dt] = __builtin_amdgcn_mfma_f32_16x16x32_bf16(
                    pf, vf[dt], O[dt], 0, 0, 0);
        }
    }

    // row-sum reduction over the 16 col16 lanes (once)
#pragma unroll
    for (int r = 0; r < 4; r++) {
#pragma unroll
        for (int o = 1; o < 16; o <<= 1)
            lrun[r] += __shfl_xor(lrun[r], o);
    }

    // O epilogue: b64 pos-layout (pos = col16*4 + dt), then gather to ctx
    const int b = bh >> 4, h = bh & 15;
#pragma unroll
    for (int r = 0; r < 4; r++) {
        const int ml = quad * 4 + r;
        const float inv = 1.0f / lrun[r];
        const u32 lo = pack2t(O[0][r] * inv, O[1][r] * inv);
        const u32 hi = pack2t(O[2][r] * inv, O[3][r] * inv);
        *(uint2*)(QP + (wid * 16 + ml) * 64 +
                  (((col16 >> 1) ^ (ml & 7)) * 8 + (col16 & 1) * 4)) =
            make_uint2(lo, hi);
    }
#pragma unroll
    for (int j = 0; j < 2; j++) {
        const int g  = j * 64 + lane;       // 128 chunks: 16 rows x 8 d-chunks
        const int sl = g >> 3;
        const int cir = g & 7;
        u32 wv[4];
#pragma unroll
        for (int hw = 0; hw < 4; hw++) {
            const int d0 = cir * 8 + hw * 2;
            const int p0 = ((d0 & 15) << 2) | (d0 >> 4);
            const int d1 = d0 + 1;
            const int p1 = ((d1 & 15) << 2) | (d1 >> 4);
            const u16 v0 = QP[(wid * 16 + sl) * 64 + ((p0 >> 3) ^ (sl & 7)) * 8 + (p0 & 7)];
            const u16 v1 = QP[(wid * 16 + sl) * 64 + ((p1 >> 3) ^ (sl & 7)) * 8 + (p1 & 7)];
            wv[hw] = (u32)v0 | ((u32)v1 << 16);
        }
        const size_t rowbase =
            ((size_t)b * S_LEN + qBase + wid * 16 + sl) * EMB + h * 64;
        *(uint4*)(ctx + rowbase + cir * 8) = make_uint4(wv[0], wv[1], wv[2], wv[3]);
    }
}

// ---------------------------------------------------------------------------
// Kernel C: out(f32) = ctx * Wo^T. 64x128 tiles, grid (64, 8) = 512 blocks.
// ---------------------------------------------------------------------------
__global__ __launch_bounds__(256) void proj_kernel(
    const u16* __restrict__ X, const u16* __restrict__ W, float* __restrict__ out)
{
    __shared__ __align__(16) u16 smem[12288];   // As 64x64 + Bs 128x64
    u16* As = smem;
    u16* Bs = smem + 64 * 64;

    const int tid   = threadIdx.x;
    const int lane  = tid & 63;
    const int wid   = tid >> 6;
    const int waveM = wid >> 1;          // 0..1
    const int waveN = wid & 1;
    const int col16 = lane & 15;
    const int quad  = lane >> 4;

    const int m0 = blockIdx.x * 64;
    const int n0 = blockIdx.y * 128;

    f32x4 acc[4][2];   // [nt][mt] (operand-swapped)
    const f32x4 zero4 = {0.f, 0.f, 0.f, 0.f};
#pragma unroll
    for (int i = 0; i < 4; i++)
#pragma unroll
        for (int j = 0; j < 2; j++) acc[i][j] = zero4;

    const int drow = tid >> 3;
    const int dpos = tid & 7;
    const u16* Ag = X + (size_t)m0 * EMB;
    const u16* Bg = W + (size_t)n0 * EMB;

    for (int k0 = 0; k0 < EMB; k0 += 64) {
        __syncthreads();
#pragma unroll
        for (int j = 0; j < 2; j++) {
            const int rl = j * 32 + drow;
            const int cg = dpos ^ (rl & 7);
            lds_dma16(Ag + (size_t)rl * EMB + k0 + cg * 8,
                      As + (j * 32 + wid * 8) * 64);
        }
#pragma unroll
        for (int j = 0; j < 4; j++) {
            const int rl = j * 32 + drow;
            const int cg = dpos ^ (rl & 7);
            lds_dma16(Bg + (size_t)rl * EMB + k0 + cg * 8,
                      Bs + (j * 32 + wid * 8) * 64);
        }
        __syncthreads();

        short8 af[2][2], bf[4][2];
#pragma unroll
        for (int mt = 0; mt < 2; mt++) {
            const int r = waveM * 32 + mt * 16 + col16;
#pragma unroll
            for (int ks = 0; ks < 2; ks++) {
                const int p = (ks * 4 + quad) ^ (r & 7);
                af[mt][ks] = *(const short8*)(As + r * 64 + p * 8);
            }
        }
#pragma unroll
        for (int nt = 0; nt < 4; nt++) {
            const int r = waveN * 64 + nt * 16 + col16;
#pragma unroll
            for (int ks = 0; ks < 2; ks++) {
                const int p = (ks * 4 + quad) ^ (r & 7);
                bf[nt][ks] = *(const short8*)(Bs + r * 64 + p * 8);
            }
        }
#pragma unroll
        for (int ks = 0; ks < 2; ks++)
#pragma unroll
            for (int nt = 0; nt < 4; nt++)
#pragma unroll
                for (int mt = 0; mt < 2; mt++)
                    acc[nt][mt] = __builtin_amdgcn_mfma_f32_16x16x32_bf16(
                        bf[nt][ks], af[mt][ks], acc[nt][mt], 0, 0, 0);
    }

#pragma unroll
    for (int nt = 0; nt < 4; nt++)
#pragma unroll
        for (int mt = 0; mt < 2; mt++) {
            const int m_g = m0 + waveM * 32 + mt * 16 + col16;
            const int n_g = n0 + waveN * 64 + nt * 16 + quad * 4;
            *(f32x4*)(out + (size_t)m_g * EMB + n_g) = acc[nt][mt];
        }
}

// ---------------------------------------------------------------------------
extern "C" void kernel_launch(void* const* d_in, const int* in_sizes, int n_in,
                              void* d_out, int out_size, void* d_ws, size_t ws_size,
                              hipStream_t stream)
{
    const float* x  = (const float*)d_in[0];
    const float* Wq = (const float*)d_in[1];
    const float* Wk = (const float*)d_in[2];
    const float* Wv = (const float*)d_in[3];
    const float* Wo = (const float*)d_in[4];

    u16* ws = (u16*)d_ws;
    u16* xb  = ws;
    u16* wb  = ws + 4194304;            // wq,wk,wv contiguous
    u16* wob = ws + 7340032;
    u16* q   = ws + 8388608;
    u16* k   = ws + 12582912;
    u16* v   = ws + 16777216;           // V^T [B,H,D,S], tau-ordered
    u16* ctx = ws + 20971520;
    float2* tab = (float2*)(ws + 25165824);   // 2048x32 float2 = 512 KB

    cast_kernel<<<dim3(2048, 6), 256, 0, stream>>>(x, Wq, Wk, Wv, Wo, ws, tab);
    qkv_rope_kernel<<<dim3(64, 24), 256, 0, stream>>>(xb, wb, tab, q, k, v);
    attn_kernel<<<dim3(32, 32), 256, 0, stream>>>(q, k, v, ctx);
    proj_kernel<<<dim3(64, 8), 256, 0, stream>>>(ctx, wob, (float*)d_out);
}

// Round 15
// 171.811 us; speedup vs baseline: 1.0666x; 1.0187x over previous
//
#include <hip/hip_runtime.h>
#include <hip/hip_bf16.h>

#define H_NUM 16
#define D_DIM 64
#define S_LEN 2048
#define EMB   1024
#define M_TOT 4096   // B * S_LEN

typedef unsigned short u16;
typedef unsigned int   u32;
typedef __attribute__((ext_vector_type(8))) short short8;   // 8 bf16 in 4 VGPRs
typedef __attribute__((ext_vector_type(4))) float f32x4;    // MFMA C/D

__device__ __forceinline__ u32 f2bf_u(float f) {
    u32 u = __float_as_uint(f);
    return (u + 0x7fffu + ((u >> 16) & 1u)) >> 16;   // RNE, low 16 valid
}
__device__ __forceinline__ u32 pack2(float a, float b) {
    return f2bf_u(a) | (f2bf_u(b) << 16);
}
// 1-instr truncating bf16 pack: low16 = bf16(a) (RTZ), high16 = bf16(b) (RTZ)
__device__ __forceinline__ u32 pack2t(float a, float b) {
    return __builtin_amdgcn_perm(__float_as_uint(b), __float_as_uint(a),
                                 0x07060302u);
}
__device__ __forceinline__ uint4 pack8(float4 lo, float4 hi) {
    return make_uint4(pack2(lo.x, lo.y), pack2(lo.z, lo.w),
                      pack2(hi.x, hi.y), pack2(hi.z, hi.w));
}

// async global->LDS, 16B per lane; lds dest = wave-uniform base + lane*16
__device__ __forceinline__ void lds_dma16(const u16* g, u16* l) {
    __builtin_amdgcn_global_load_lds(
        (const __attribute__((address_space(1))) void*)g,
        (__attribute__((address_space(3))) void*)l, 16, 0, 0);
}

// ---------------------------------------------------------------------------
// Kernel 0: cast f32 inputs -> bf16 ws copies; seg 5 builds RoPE cos/sin table
// ---------------------------------------------------------------------------
__global__ __launch_bounds__(256) void cast_kernel(
    const float* __restrict__ x,  const float* __restrict__ Wq,
    const float* __restrict__ Wk, const float* __restrict__ Wv,
    const float* __restrict__ Wo, u16* __restrict__ ws, float2* __restrict__ tab)
{
    const int seg = blockIdx.y;
    if (seg == 5) {
        const int idx = blockIdx.x * 256 + threadIdx.x;
        if (idx < S_LEN * 32) {
            const int s = idx >> 5, d = idx & 31;
            const float ang = (float)s * __expf(-(float)d * 0.28782313662425573f);
            tab[idx] = make_float2(cosf(ang), sinf(ang));
        }
        return;
    }
    const float* src = (seg == 0) ? x : (seg == 1) ? Wq : (seg == 2) ? Wk
                     : (seg == 3) ? Wv : Wo;
    u16* dst = (seg == 0) ? ws : ws + (3 + seg) * 1048576;   // xb@0, W*@4M..7M
    const int n = (seg == 0) ? 4194304 : 1048576;
    const int idx = (blockIdx.x * 256 + threadIdx.x) * 8;
    if (idx < n) {
        float4 lo = *(const float4*)(src + idx);
        float4 hi = *(const float4*)(src + idx + 4);
        *(uint4*)(dst + idx) = pack8(lo, hi);
    }
}

// ---------------------------------------------------------------------------
// Kernel A: GEMM, 64x128 tiles; grid (64,24) = 1536 blocks = 6/CU, LDS 24 KB.
// x = m-block (XCD=m%8), y = z*8 + n.
// w==2 (V) stores V^T [B,H,D,S] tau-permuted (tau(p)=((p&3)<<4)|(p>>2)).
// ---------------------------------------------------------------------------
__global__ __launch_bounds__(256) void qkv_rope_kernel(
    const u16* __restrict__ xb, const u16* __restrict__ wb,
    const float2* __restrict__ tab,
    u16* __restrict__ qo, u16* __restrict__ ko, u16* __restrict__ vo)
{
    const int w  = blockIdx.y >> 3;         // 0..2
    const int nb = blockIdx.y & 7;          // 0..7
    const u16* W = wb + w * 1048576;

    __shared__ __align__(16) u16 smem[12288];   // As 4K + Bs 8K u16; Ep 64x132
    u16* As = smem;
    u16* Bs = smem + 64 * 64;
    u16 (*Ep)[132] = (u16(*)[132])smem;

    const int tid   = threadIdx.x;
    const int lane  = tid & 63;
    const int wid   = tid >> 6;
    const int waveM = wid >> 1;          // 0..1 (32-row slice)
    const int waveN = wid & 1;           // 0..1 (64-col slice)
    const int col16 = lane & 15;
    const int quad  = lane >> 4;

    const int m0 = blockIdx.x * 64;
    const int n0 = nb * 128;

    f32x4 acc[2][4];
    const f32x4 zero4 = {0.f, 0.f, 0.f, 0.f};
#pragma unroll
    for (int i = 0; i < 2; i++)
#pragma unroll
        for (int j = 0; j < 4; j++) acc[i][j] = zero4;

    const int drow = tid >> 3;          // 0..31
    const int dpos = tid & 7;
    const u16* Ag = xb + (size_t)m0 * EMB;
    const u16* Bg = W  + (size_t)n0 * EMB;

    for (int k0 = 0; k0 < EMB; k0 += 64) {
        __syncthreads();
#pragma unroll
        for (int j = 0; j < 2; j++) {
            const int rl = j * 32 + drow;
            const int cg = dpos ^ (rl & 7);
            lds_dma16(Ag + (size_t)rl * EMB + k0 + cg * 8,
                      As + (j * 32 + wid * 8) * 64);
        }
#pragma unroll
        for (int j = 0; j < 4; j++) {
            const int rl = j * 32 + drow;
            const int cg = dpos ^ (rl & 7);
            lds_dma16(Bg + (size_t)rl * EMB + k0 + cg * 8,
                      Bs + (j * 32 + wid * 8) * 64);
        }
        __syncthreads();

        short8 af[2][2], bf[4][2];
#pragma unroll
        for (int mt = 0; mt < 2; mt++) {
            const int r = waveM * 32 + mt * 16 + col16;
#pragma unroll
            for (int ks = 0; ks < 2; ks++) {
                const int p = (ks * 4 + quad) ^ (r & 7);
                af[mt][ks] = *(const short8*)(As + r * 64 + p * 8);
            }
        }
#pragma unroll
        for (int nt = 0; nt < 4; nt++) {
            const int r = waveN * 64 + nt * 16 + col16;
#pragma unroll
            for (int ks = 0; ks < 2; ks++) {
                const int p = (ks * 4 + quad) ^ (r & 7);
                bf[nt][ks] = *(const short8*)(Bs + r * 64 + p * 8);
            }
        }
#pragma unroll
        for (int ks = 0; ks < 2; ks++)
#pragma unroll
            for (int mt = 0; mt < 2; mt++)
#pragma unroll
                for (int nt = 0; nt < 4; nt++)
                    acc[mt][nt] = __builtin_amdgcn_mfma_f32_16x16x32_bf16(
                        af[mt][ks], bf[nt][ks], acc[mt][nt], 0, 0, 0);
    }

    // ---- epilogue: RoPE (table) + LDS round trip + 16B coalesced stores ----
    __syncthreads();
#pragma unroll
    for (int mt = 0; mt < 2; mt++) {
#pragma unroll
        for (int r = 0; r < 4; r++) {
            const int m_local = waveM * 32 + mt * 16 + quad * 4 + r;
            const int s = (m0 + m_local) & 2047;
            if (w == 2) {
#pragma unroll
                for (int nt = 0; nt < 4; nt++)
                    Ep[m_local][waveN * 64 + nt * 16 + col16] =
                        (u16)f2bf_u(acc[mt][nt][r]);
            } else {
#pragma unroll
                for (int nt = 0; nt < 2; nt++) {
                    const int d = nt * 16 + col16;          // [0,32)
                    const float2 cs = tab[s * 32 + d];
                    const float lo = acc[mt][nt][r];
                    const float hi = acc[mt][nt + 2][r];
                    Ep[m_local][waveN * 64 + d]      = (u16)f2bf_u(lo * cs.x - hi * cs.y);
                    Ep[m_local][waveN * 64 + d + 32] = (u16)f2bf_u(hi * cs.x + lo * cs.y);
                }
            }
        }
    }
    __syncthreads();

    const int b = m0 >> 11;
    if (w != 2) {
        u16* out = (w == 0) ? qo : ko;
#pragma unroll
        for (int j = 0; j < 4; j++) {
            const int g = j * 256 + tid;        // [0,1024): 2 heads x 64 s x 8
            const int head_local = g >> 9;
            const int sl  = (g >> 3) & 63;
            const int cir = g & 7;
            uint4 val = *(const uint4*)(&Ep[sl][head_local * 64 + cir * 8]);
            const int h = (n0 >> 6) + head_local;
            const size_t base = (((size_t)(b * H_NUM + h)) * S_LEN + (m0 & 2047)) * 64;
            *(uint4*)(out + base + (size_t)(g & 511) * 8) = val;
        }
    } else {
        // V^T store: vo[((b*16+h)*64+d)*2048 + s]; one tau 64-block (s-span 64)
        const int s0 = m0 & 2047;
#pragma unroll
        for (int j = 0; j < 4; j++) {
            const int g = j * 256 + tid;        // [0,1024): d_all(128) x sc(8)
            const int d_all = g >> 3;           // 0..127
            const int sc = g & 7;               // s-chunk of 8
            u32 wv[4];
#pragma unroll
            for (int hw = 0; hw < 4; hw++) {
                const int p0 = sc * 8 + hw * 2;
                const int r0 = ((p0 & 3) << 4) | (p0 >> 2);
                const int p1 = p0 + 1;
                const int r1 = ((p1 & 3) << 4) | (p1 >> 2);
                wv[hw] = (u32)Ep[r0][d_all] | ((u32)Ep[r1][d_all] << 16);
            }
            const int h = (n0 >> 6) + (d_all >> 6);
            const int d = d_all & 63;
            *(uint4*)(vo + ((size_t)(b * H_NUM + h) * 64 + d) * 2048 + s0 + sc * 8) =
                make_uint4(wv[0], wv[1], wv[2], wv[3]);
        }
    }
}

// ---------------------------------------------------------------------------
// Kernel B: causal flash attention. R15 = R14 + double-buffered K/V^T with
// post-barrier prefetch: DMA for tile kt+1 issued right after the barrier
// that drains tile kt, so the mandatory vmcnt(0)-at-barrier finds it done.
// LDS 40 KB -> still 4 blocks/CU (160 KB exactly).
// ---------------------------------------------------------------------------
__global__ __launch_bounds__(256) void attn_kernel(
    const u16* __restrict__ q, const u16* __restrict__ k,
    const u16* __restrict__ v, u16* __restrict__ ctx)
{
    __shared__ __align__(16) u16 QP[64 * 64];     // Q staging, then per-wave P/O
    __shared__ __align__(16) u16 Ks[2][64 * 64];  // double-buffered K
    __shared__ __align__(16) u16 VTs[2][64 * 64]; // double-buffered V^T

    const int tid   = threadIdx.x;
    const int lane  = tid & 63;
    const int wid   = tid >> 6;
    const int col16 = lane & 15;
    const int quad  = lane >> 4;

    const int bh    = blockIdx.x;
    const int qb    = 31 - blockIdx.y;     // heavy blocks dispatch first
    const int qBase = qb * 64;
    const size_t bhOff = (size_t)bh * S_LEN * D_DIM;   // same for V^T (64*2048)

    const int drow = tid >> 3;          // 0..31
    const int dpos = tid & 7;

    auto stage = [&](int kt, int buf) {
#pragma unroll
        for (int j = 0; j < 2; j++) {
            const int rl = j * 32 + drow;
            const int cg = dpos ^ (rl & 7);
            lds_dma16(k + bhOff + (size_t)(kt * 64 + rl) * 64 + cg * 8,
                      &Ks[buf][(j * 32 + wid * 8) * 64]);
        }
#pragma unroll
        for (int j = 0; j < 2; j++) {
            const int rl = j * 32 + drow;
            const int cg = dpos ^ (rl & 7);
            lds_dma16(v + bhOff + (size_t)rl * 2048 + kt * 64 + cg * 8,
                      &VTs[buf][(j * 32 + wid * 8) * 64]);
        }
    };

    // issue tile-0 K/V DMA + Q DMA together; one drain covers both
    stage(0, 0);
#pragma unroll
    for (int j = 0; j < 2; j++) {
        const int rl = j * 32 + drow;
        const int cg = dpos ^ (rl & 7);
        lds_dma16(q + bhOff + (size_t)(qBase + rl) * 64 + cg * 8,
                  QP + (j * 32 + wid * 8) * 64);
    }
    __syncthreads();   // Q + tile0 ready

    short8 qf[2];
    {
        const int rq = wid * 16 + col16;
#pragma unroll
        for (int ks = 0; ks < 2; ks++) {
            const int c = (ks * 4 + quad) ^ (rq & 7);
            qf[ks] = *(const short8*)(QP + rq * 64 + c * 8);
        }
    }

    f32x4 O[4];
    const f32x4 zero4 = {0.f, 0.f, 0.f, 0.f};
#pragma unroll
    for (int j = 0; j < 4; j++) O[j] = zero4;
    float lrun[4] = {0.f, 0.f, 0.f, 0.f};

    const float K2 = 0.18033688011112042f;   // 0.125 * log2(e)

    for (int kt = 0; kt <= qb; kt++) {
        // top barrier (kt>0): drains tile-kt DMA and fences compute(kt-1) reads
        if (kt > 0) __syncthreads();
        // prefetch next tile into the other buffer; flies during compute(kt)
        if (kt < qb) stage(kt + 1, (kt + 1) & 1);
        const int cur = kt & 1;

        f32x4 sc[4];
#pragma unroll
        for (int nt = 0; nt < 4; nt++) sc[nt] = zero4;
#pragma unroll
        for (int ks = 0; ks < 2; ks++) {
            short8 kf[4];
#pragma unroll
            for (int nt = 0; nt < 4; nt++) {
                const int rk = nt * 16 + col16;
                const int c = (ks * 4 + quad) ^ (rk & 7);
                kf[nt] = *(const short8*)(&Ks[cur][rk * 64 + c * 8]);
            }
#pragma unroll
            for (int nt = 0; nt < 4; nt++)
                sc[nt] = __builtin_amdgcn_mfma_f32_16x16x32_bf16(
                    qf[ks], kf[nt], sc[nt], 0, 0, 0);
        }

        // fixed-max log2-domain softmax; mask only on the diagonal tile
        if (kt == qb) {
#pragma unroll
            for (int r = 0; r < 4; r++) {
                const int qg = qBase + wid * 16 + quad * 4 + r;
                float lsum = 0.f;
#pragma unroll
                for (int nt = 0; nt < 4; nt++) {
                    const int kg = kt * 64 + nt * 16 + col16;
                    float sv = fmaf(sc[nt][r], K2, -16.0f);
                    if (kg > qg) sv = -INFINITY;
                    const float p = exp2f(sv);
                    sc[nt][r] = p;
                    lsum += p;
                }
                lrun[r] += lsum;
            }
        } else {
#pragma unroll
            for (int r = 0; r < 4; r++) {
                float lsum = 0.f;
#pragma unroll
                for (int nt = 0; nt < 4; nt++) {
                    const float p = exp2f(fmaf(sc[nt][r], K2, -16.0f));
                    sc[nt][r] = p;
                    lsum += p;
                }
                lrun[r] += lsum;
            }
        }

        // P -> wave-private LDS rows, b64 at pos=col16*4+nt (tau-order)
#pragma unroll
        for (int r = 0; r < 4; r++) {
            const int ml = quad * 4 + r;
            const u32 lo = pack2t(sc[0][r], sc[1][r]);
            const u32 hi = pack2t(sc[2][r], sc[3][r]);
            *(uint2*)(QP + (wid * 16 + ml) * 64 +
                      (((col16 >> 1) ^ (ml & 7)) * 8 + (col16 & 1) * 4)) =
                make_uint2(lo, hi);
        }

#pragma unroll
        for (int ks = 0; ks < 2; ks++) {
            short8 pf, vf[4];
            {
                const int c = (ks * 4 + quad) ^ (col16 & 7);
                pf = *(const short8*)(QP + (wid * 16 + col16) * 64 + c * 8);
            }
#pragma unroll
            for (int dt = 0; dt < 4; dt++) {
                const int d = dt * 16 + col16;
                const int c = (ks * 4 + quad) ^ (d & 7);
                vf[dt] = *(const short8*)(&VTs[cur][d * 64 + c * 8]);
            }
#pragma unroll
            for (int dt = 0; dt < 4; dt++)
                O[dt] = __builtin_amdgcn_mfma_f32_16x16x32_bf16(
                    pf, vf[dt], O[dt], 0, 0, 0);
        }
    }

    // row-sum reduction over the 16 col16 lanes (once)
#pragma unroll
    for (int r = 0; r < 4; r++) {
#pragma unroll
        for (int o = 1; o < 16; o <<= 1)
            lrun[r] += __shfl_xor(lrun[r], o);
    }

    // O epilogue: b64 pos-layout (pos = col16*4 + dt), then gather to ctx
    const int b = bh >> 4, h = bh & 15;
#pragma unroll
    for (int r = 0; r < 4; r++) {
        const int ml = quad * 4 + r;
        const float inv = 1.0f / lrun[r];
        const u32 lo = pack2t(O[0][r] * inv, O[1][r] * inv);
        const u32 hi = pack2t(O[2][r] * inv, O[3][r] * inv);
        *(uint2*)(QP + (wid * 16 + ml) * 64 +
                  (((col16 >> 1) ^ (ml & 7)) * 8 + (col16 & 1) * 4)) =
            make_uint2(lo, hi);
    }
#pragma unroll
    for (int j = 0; j < 2; j++) {
        const int g  = j * 64 + lane;       // 128 chunks: 16 rows x 8 d-chunks
        const int sl = g >> 3;
        const int cir = g & 7;
        u32 wv[4];
#pragma unroll
        for (int hw = 0; hw < 4; hw++) {
            const int d0 = cir * 8 + hw * 2;
            const int p0 = ((d0 & 15) << 2) | (d0 >> 4);
            const int d1 = d0 + 1;
            const int p1 = ((d1 & 15) << 2) | (d1 >> 4);
            const u16 v0 = QP[(wid * 16 + sl) * 64 + ((p0 >> 3) ^ (sl & 7)) * 8 + (p0 & 7)];
            const u16 v1 = QP[(wid * 16 + sl) * 64 + ((p1 >> 3) ^ (sl & 7)) * 8 + (p1 & 7)];
            wv[hw] = (u32)v0 | ((u32)v1 << 16);
        }
        const size_t rowbase =
            ((size_t)b * S_LEN + qBase + wid * 16 + sl) * EMB + h * 64;
        *(uint4*)(ctx + rowbase + cir * 8) = make_uint4(wv[0], wv[1], wv[2], wv[3]);
    }
}

// ---------------------------------------------------------------------------
// Kernel C: out(f32) = ctx * Wo^T. 64x128 tiles, grid (64, 8) = 512 blocks.
// ---------------------------------------------------------------------------
__global__ __launch_bounds__(256) void proj_kernel(
    const u16* __restrict__ X, const u16* __restrict__ W, float* __restrict__ out)
{
    __shared__ __align__(16) u16 smem[12288];   // As 64x64 + Bs 128x64
    u16* As = smem;
    u16* Bs = smem + 64 * 64;

    const int tid   = threadIdx.x;
    const int lane  = tid & 63;
    const int wid   = tid >> 6;
    const int waveM = wid >> 1;          // 0..1
    const int waveN = wid & 1;
    const int col16 = lane & 15;
    const int quad  = lane >> 4;

    const int m0 = blockIdx.x * 64;
    const int n0 = blockIdx.y * 128;

    f32x4 acc[4][2];   // [nt][mt] (operand-swapped)
    const f32x4 zero4 = {0.f, 0.f, 0.f, 0.f};
#pragma unroll
    for (int i = 0; i < 4; i++)
#pragma unroll
        for (int j = 0; j < 2; j++) acc[i][j] = zero4;

    const int drow = tid >> 3;
    const int dpos = tid & 7;
    const u16* Ag = X + (size_t)m0 * EMB;
    const u16* Bg = W + (size_t)n0 * EMB;

    for (int k0 = 0; k0 < EMB; k0 += 64) {
        __syncthreads();
#pragma unroll
        for (int j = 0; j < 2; j++) {
            const int rl = j * 32 + drow;
            const int cg = dpos ^ (rl & 7);
            lds_dma16(Ag + (size_t)rl * EMB + k0 + cg * 8,
                      As + (j * 32 + wid * 8) * 64);
        }
#pragma unroll
        for (int j = 0; j < 4; j++) {
            const int rl = j * 32 + drow;
            const int cg = dpos ^ (rl & 7);
            lds_dma16(Bg + (size_t)rl * EMB + k0 + cg * 8,
                      Bs + (j * 32 + wid * 8) * 64);
        }
        __syncthreads();

        short8 af[2][2], bf[4][2];
#pragma unroll
        for (int mt = 0; mt < 2; mt++) {
            const int r = waveM * 32 + mt * 16 + col16;
#pragma unroll
            for (int ks = 0; ks < 2; ks++) {
                const int p = (ks * 4 + quad) ^ (r & 7);
                af[mt][ks] = *(const short8*)(As + r * 64 + p * 8);
            }
        }
#pragma unroll
        for (int nt = 0; nt < 4; nt++) {
            const int r = waveN * 64 + nt * 16 + col16;
#pragma unroll
            for (int ks = 0; ks < 2; ks++) {
                const int p = (ks * 4 + quad) ^ (r & 7);
                bf[nt][ks] = *(const short8*)(Bs + r * 64 + p * 8);
            }
        }
#pragma unroll
        for (int ks = 0; ks < 2; ks++)
#pragma unroll
            for (int nt = 0; nt < 4; nt++)
#pragma unroll
                for (int mt = 0; mt < 2; mt++)
                    acc[nt][mt] = __builtin_amdgcn_mfma_f32_16x16x32_bf16(
                        bf[nt][ks], af[mt][ks], acc[nt][mt], 0, 0, 0);
    }

#pragma unroll
    for (int nt = 0; nt < 4; nt++)
#pragma unroll
        for (int mt = 0; mt < 2; mt++) {
            const int m_g = m0 + waveM * 32 + mt * 16 + col16;
            const int n_g = n0 + waveN * 64 + nt * 16 + quad * 4;
            *(f32x4*)(out + (size_t)m_g * EMB + n_g) = acc[nt][mt];
        }
}

// ---------------------------------------------------------------------------
extern "C" void kernel_launch(void* const* d_in, const int* in_sizes, int n_in,
                              void* d_out, int out_size, void* d_ws, size_t ws_size,
                              hipStream_t stream)
{
    const float* x  = (const float*)d_in[0];
    const float* Wq = (const float*)d_in[1];
    const float* Wk = (const float*)d_in[2];
    const float* Wv = (const float*)d_in[3];
    const float* Wo = (const float*)d_in[4];

    u16* ws = (u16*)d_ws;
    u16* xb  = ws;
    u16* wb  = ws + 4194304;            // wq,wk,wv contiguous
    u16* wob = ws + 7340032;
    u16* q   = ws + 8388608;
    u16* k   = ws + 12582912;
    u16* v   = ws + 16777216;           // V^T [B,H,D,S], tau-ordered
    u16* ctx = ws + 20971520;
    float2* tab = (float2*)(ws + 25165824);   // 2048x32 float2 = 512 KB

    cast_kernel<<<dim3(2048, 6), 256, 0, stream>>>(x, Wq, Wk, Wv, Wo, ws, tab);
    qkv_rope_kernel<<<dim3(64, 24), 256, 0, stream>>>(xb, wb, tab, q, k, v);
    attn_kernel<<<dim3(32, 32), 256, 0, stream>>>(q, k, v, ctx);
    proj_kernel<<<dim3(64, 8), 256, 0, stream>>>(ctx, wob, (float*)d_out);
}

// Round 16
// 170.038 us; speedup vs baseline: 1.0777x; 1.0104x over previous
//
#include <hip/hip_runtime.h>
#include <hip/hip_bf16.h>

#define H_NUM 16
#define D_DIM 64
#define S_LEN 2048
#define EMB   1024
#define M_TOT 4096   // B * S_LEN

typedef unsigned short u16;
typedef unsigned int   u32;
typedef __attribute__((ext_vector_type(8))) short short8;   // 8 bf16 in 4 VGPRs
typedef __attribute__((ext_vector_type(4))) float f32x4;    // MFMA C/D

__device__ __forceinline__ u32 f2bf_u(float f) {
    u32 u = __float_as_uint(f);
    return (u + 0x7fffu + ((u >> 16) & 1u)) >> 16;   // RNE, low 16 valid
}
__device__ __forceinline__ u32 pack2(float a, float b) {
    return f2bf_u(a) | (f2bf_u(b) << 16);
}
// 1-instr truncating bf16 pack: low16 = bf16(a) (RTZ), high16 = bf16(b) (RTZ)
__device__ __forceinline__ u32 pack2t(float a, float b) {
    return __builtin_amdgcn_perm(__float_as_uint(b), __float_as_uint(a),
                                 0x07060302u);
}
__device__ __forceinline__ uint4 pack8(float4 lo, float4 hi) {
    return make_uint4(pack2(lo.x, lo.y), pack2(lo.z, lo.w),
                      pack2(hi.x, hi.y), pack2(hi.z, hi.w));
}

// async global->LDS, 16B per lane; lds dest = wave-uniform base + lane*16
__device__ __forceinline__ void lds_dma16(const u16* g, u16* l) {
    __builtin_amdgcn_global_load_lds(
        (const __attribute__((address_space(1))) void*)g,
        (__attribute__((address_space(3))) void*)l, 16, 0, 0);
}

// ---------------------------------------------------------------------------
// Kernel 0: cast f32 inputs -> bf16 ws copies; seg 5 builds RoPE cos/sin table
// ---------------------------------------------------------------------------
__global__ __launch_bounds__(256) void cast_kernel(
    const float* __restrict__ x,  const float* __restrict__ Wq,
    const float* __restrict__ Wk, const float* __restrict__ Wv,
    const float* __restrict__ Wo, u16* __restrict__ ws, float2* __restrict__ tab)
{
    const int seg = blockIdx.y;
    if (seg == 5) {
        const int idx = blockIdx.x * 256 + threadIdx.x;
        if (idx < S_LEN * 32) {
            const int s = idx >> 5, d = idx & 31;
            const float ang = (float)s * __expf(-(float)d * 0.28782313662425573f);
            tab[idx] = make_float2(cosf(ang), sinf(ang));
        }
        return;
    }
    const float* src = (seg == 0) ? x : (seg == 1) ? Wq : (seg == 2) ? Wk
                     : (seg == 3) ? Wv : Wo;
    u16* dst = (seg == 0) ? ws : ws + (3 + seg) * 1048576;   // xb@0, W*@4M..7M
    const int n = (seg == 0) ? 4194304 : 1048576;
    const int idx = (blockIdx.x * 256 + threadIdx.x) * 8;
    if (idx < n) {
        float4 lo = *(const float4*)(src + idx);
        float4 hi = *(const float4*)(src + idx + 4);
        *(uint4*)(dst + idx) = pack8(lo, hi);
    }
}

// ---------------------------------------------------------------------------
// Kernel A: GEMM, 64x128 tiles; grid (64,24) = 1536 blocks = 6/CU, LDS 24 KB.
// x = m-block (XCD=m%8), y = z*8 + n.
// w==2 (V) stores V^T [B,H,D,S] tau-permuted (tau(p)=((p&3)<<4)|(p>>2)).
// ---------------------------------------------------------------------------
__global__ __launch_bounds__(256) void qkv_rope_kernel(
    const u16* __restrict__ xb, const u16* __restrict__ wb,
    const float2* __restrict__ tab,
    u16* __restrict__ qo, u16* __restrict__ ko, u16* __restrict__ vo)
{
    const int w  = blockIdx.y >> 3;         // 0..2
    const int nb = blockIdx.y & 7;          // 0..7
    const u16* W = wb + w * 1048576;

    __shared__ __align__(16) u16 smem[12288];   // As 4K + Bs 8K u16; Ep 64x132
    u16* As = smem;
    u16* Bs = smem + 64 * 64;
    u16 (*Ep)[132] = (u16(*)[132])smem;

    const int tid   = threadIdx.x;
    const int lane  = tid & 63;
    const int wid   = tid >> 6;
    const int waveM = wid >> 1;          // 0..1 (32-row slice)
    const int waveN = wid & 1;           // 0..1 (64-col slice)
    const int col16 = lane & 15;
    const int quad  = lane >> 4;

    const int m0 = blockIdx.x * 64;
    const int n0 = nb * 128;

    f32x4 acc[2][4];
    const f32x4 zero4 = {0.f, 0.f, 0.f, 0.f};
#pragma unroll
    for (int i = 0; i < 2; i++)
#pragma unroll
        for (int j = 0; j < 4; j++) acc[i][j] = zero4;

    const int drow = tid >> 3;          // 0..31
    const int dpos = tid & 7;
    const u16* Ag = xb + (size_t)m0 * EMB;
    const u16* Bg = W  + (size_t)n0 * EMB;

    for (int k0 = 0; k0 < EMB; k0 += 64) {
        __syncthreads();
#pragma unroll
        for (int j = 0; j < 2; j++) {
            const int rl = j * 32 + drow;
            const int cg = dpos ^ (rl & 7);
            lds_dma16(Ag + (size_t)rl * EMB + k0 + cg * 8,
                      As + (j * 32 + wid * 8) * 64);
        }
#pragma unroll
        for (int j = 0; j < 4; j++) {
            const int rl = j * 32 + drow;
            const int cg = dpos ^ (rl & 7);
            lds_dma16(Bg + (size_t)rl * EMB + k0 + cg * 8,
                      Bs + (j * 32 + wid * 8) * 64);
        }
        __syncthreads();

        short8 af[2][2], bf[4][2];
#pragma unroll
        for (int mt = 0; mt < 2; mt++) {
            const int r = waveM * 32 + mt * 16 + col16;
#pragma unroll
            for (int ks = 0; ks < 2; ks++) {
                const int p = (ks * 4 + quad) ^ (r & 7);
                af[mt][ks] = *(const short8*)(As + r * 64 + p * 8);
            }
        }
#pragma unroll
        for (int nt = 0; nt < 4; nt++) {
            const int r = waveN * 64 + nt * 16 + col16;
#pragma unroll
            for (int ks = 0; ks < 2; ks++) {
                const int p = (ks * 4 + quad) ^ (r & 7);
                bf[nt][ks] = *(const short8*)(Bs + r * 64 + p * 8);
            }
        }
#pragma unroll
        for (int ks = 0; ks < 2; ks++)
#pragma unroll
            for (int mt = 0; mt < 2; mt++)
#pragma unroll
                for (int nt = 0; nt < 4; nt++)
                    acc[mt][nt] = __builtin_amdgcn_mfma_f32_16x16x32_bf16(
                        af[mt][ks], bf[nt][ks], acc[mt][nt], 0, 0, 0);
    }

    // ---- epilogue: RoPE (table) + LDS round trip + 16B coalesced stores ----
    __syncthreads();
#pragma unroll
    for (int mt = 0; mt < 2; mt++) {
#pragma unroll
        for (int r = 0; r < 4; r++) {
            const int m_local = waveM * 32 + mt * 16 + quad * 4 + r;
            const int s = (m0 + m_local) & 2047;
            if (w == 2) {
#pragma unroll
                for (int nt = 0; nt < 4; nt++)
                    Ep[m_local][waveN * 64 + nt * 16 + col16] =
                        (u16)f2bf_u(acc[mt][nt][r]);
            } else {
#pragma unroll
                for (int nt = 0; nt < 2; nt++) {
                    const int d = nt * 16 + col16;          // [0,32)
                    const float2 cs = tab[s * 32 + d];
                    const float lo = acc[mt][nt][r];
                    const float hi = acc[mt][nt + 2][r];
                    Ep[m_local][waveN * 64 + d]      = (u16)f2bf_u(lo * cs.x - hi * cs.y);
                    Ep[m_local][waveN * 64 + d + 32] = (u16)f2bf_u(hi * cs.x + lo * cs.y);
                }
            }
        }
    }
    __syncthreads();

    const int b = m0 >> 11;
    if (w != 2) {
        u16* out = (w == 0) ? qo : ko;
#pragma unroll
        for (int j = 0; j < 4; j++) {
            const int g = j * 256 + tid;        // [0,1024): 2 heads x 64 s x 8
            const int head_local = g >> 9;
            const int sl  = (g >> 3) & 63;
            const int cir = g & 7;
            uint4 val = *(const uint4*)(&Ep[sl][head_local * 64 + cir * 8]);
            const int h = (n0 >> 6) + head_local;
            const size_t base = (((size_t)(b * H_NUM + h)) * S_LEN + (m0 & 2047)) * 64;
            *(uint4*)(out + base + (size_t)(g & 511) * 8) = val;
        }
    } else {
        // V^T store: vo[((b*16+h)*64+d)*2048 + s]; one tau 64-block (s-span 64)
        const int s0 = m0 & 2047;
#pragma unroll
        for (int j = 0; j < 4; j++) {
            const int g = j * 256 + tid;        // [0,1024): d_all(128) x sc(8)
            const int d_all = g >> 3;           // 0..127
            const int sc = g & 7;               // s-chunk of 8
            u32 wv[4];
#pragma unroll
            for (int hw = 0; hw < 4; hw++) {
                const int p0 = sc * 8 + hw * 2;
                const int r0 = ((p0 & 3) << 4) | (p0 >> 2);
                const int p1 = p0 + 1;
                const int r1 = ((p1 & 3) << 4) | (p1 >> 2);
                wv[hw] = (u32)Ep[r0][d_all] | ((u32)Ep[r1][d_all] << 16);
            }
            const int h = (n0 >> 6) + (d_all >> 6);
            const int d = d_all & 63;
            *(uint4*)(vo + ((size_t)(b * H_NUM + h) * 64 + d) * 2048 + s0 + sc * 8) =
                make_uint4(wv[0], wv[1], wv[2], wv[3]);
        }
    }
}

// ---------------------------------------------------------------------------
// Kernel B: causal flash attention. R16: balanced qb permutation — per-CU
// block quartets {y0, y0+8, y0+16, y0+24} all sum to 66 tiles (was 52..80).
// XCD affinity (x%8) unchanged. Double-buffered K/V^T prefetch (R15).
// ---------------------------------------------------------------------------
__global__ __launch_bounds__(256) void attn_kernel(
    const u16* __restrict__ q, const u16* __restrict__ k,
    const u16* __restrict__ v, u16* __restrict__ ctx)
{
    __shared__ __align__(16) u16 QP[64 * 64];     // Q staging, then per-wave P/O
    __shared__ __align__(16) u16 Ks[2][64 * 64];  // double-buffered K
    __shared__ __align__(16) u16 VTs[2][64 * 64]; // double-buffered V^T

    const int tid   = threadIdx.x;
    const int lane  = tid & 63;
    const int wid   = tid >> 6;
    const int col16 = lane & 15;
    const int quad  = lane >> 4;

    const int bh = blockIdx.x;
    // balanced mapping: o = y&7, g = y>>3 -> qb in {31-o, 16+o, 15-o, o}
    const int y = blockIdx.y;
    const int o = y & 7, g = y >> 3;
    const int qb = (g == 0) ? (31 - o) : (g == 1) ? (16 + o)
                 : (g == 2) ? (15 - o) : o;
    const int qBase = qb * 64;
    const size_t bhOff = (size_t)bh * S_LEN * D_DIM;   // same for V^T (64*2048)

    const int drow = tid >> 3;          // 0..31
    const int dpos = tid & 7;

    auto stage = [&](int kt, int buf) {
#pragma unroll
        for (int j = 0; j < 2; j++) {
            const int rl = j * 32 + drow;
            const int cg = dpos ^ (rl & 7);
            lds_dma16(k + bhOff + (size_t)(kt * 64 + rl) * 64 + cg * 8,
                      &Ks[buf][(j * 32 + wid * 8) * 64]);
        }
#pragma unroll
        for (int j = 0; j < 2; j++) {
            const int rl = j * 32 + drow;
            const int cg = dpos ^ (rl & 7);
            lds_dma16(v + bhOff + (size_t)rl * 2048 + kt * 64 + cg * 8,
                      &VTs[buf][(j * 32 + wid * 8) * 64]);
        }
    };

    // issue tile-0 K/V DMA + Q DMA together; one drain covers both
    stage(0, 0);
#pragma unroll
    for (int j = 0; j < 2; j++) {
        const int rl = j * 32 + drow;
        const int cg = dpos ^ (rl & 7);
        lds_dma16(q + bhOff + (size_t)(qBase + rl) * 64 + cg * 8,
                  QP + (j * 32 + wid * 8) * 64);
    }
    __syncthreads();   // Q + tile0 ready

    short8 qf[2];
    {
        const int rq = wid * 16 + col16;
#pragma unroll
        for (int ks = 0; ks < 2; ks++) {
            const int c = (ks * 4 + quad) ^ (rq & 7);
            qf[ks] = *(const short8*)(QP + rq * 64 + c * 8);
        }
    }

    f32x4 O[4];
    const f32x4 zero4 = {0.f, 0.f, 0.f, 0.f};
#pragma unroll
    for (int j = 0; j < 4; j++) O[j] = zero4;
    float lrun[4] = {0.f, 0.f, 0.f, 0.f};

    const float K2 = 0.18033688011112042f;   // 0.125 * log2(e)

    for (int kt = 0; kt <= qb; kt++) {
        // top barrier (kt>0): drains tile-kt DMA and fences compute(kt-1) reads
        if (kt > 0) __syncthreads();
        // prefetch next tile into the other buffer; flies during compute(kt)
        if (kt < qb) stage(kt + 1, (kt + 1) & 1);
        const int cur = kt & 1;

        f32x4 sc[4];
#pragma unroll
        for (int nt = 0; nt < 4; nt++) sc[nt] = zero4;
#pragma unroll
        for (int ks = 0; ks < 2; ks++) {
            short8 kf[4];
#pragma unroll
            for (int nt = 0; nt < 4; nt++) {
                const int rk = nt * 16 + col16;
                const int c = (ks * 4 + quad) ^ (rk & 7);
                kf[nt] = *(const short8*)(&Ks[cur][rk * 64 + c * 8]);
            }
#pragma unroll
            for (int nt = 0; nt < 4; nt++)
                sc[nt] = __builtin_amdgcn_mfma_f32_16x16x32_bf16(
                    qf[ks], kf[nt], sc[nt], 0, 0, 0);
        }

        // fixed-max log2-domain softmax; mask only on the diagonal tile
        if (kt == qb) {
#pragma unroll
            for (int r = 0; r < 4; r++) {
                const int qg = qBase + wid * 16 + quad * 4 + r;
                float lsum = 0.f;
#pragma unroll
                for (int nt = 0; nt < 4; nt++) {
                    const int kg = kt * 64 + nt * 16 + col16;
                    float sv = fmaf(sc[nt][r], K2, -16.0f);
                    if (kg > qg) sv = -INFINITY;
                    const float p = exp2f(sv);
                    sc[nt][r] = p;
                    lsum += p;
                }
                lrun[r] += lsum;
            }
        } else {
#pragma unroll
            for (int r = 0; r < 4; r++) {
                float lsum = 0.f;
#pragma unroll
                for (int nt = 0; nt < 4; nt++) {
                    const float p = exp2f(fmaf(sc[nt][r], K2, -16.0f));
                    sc[nt][r] = p;
                    lsum += p;
                }
                lrun[r] += lsum;
            }
        }

        // P -> wave-private LDS rows, b64 at pos=col16*4+nt (tau-order)
#pragma unroll
        for (int r = 0; r < 4; r++) {
            const int ml = quad * 4 + r;
            const u32 lo = pack2t(sc[0][r], sc[1][r]);
            const u32 hi = pack2t(sc[2][r], sc[3][r]);
            *(uint2*)(QP + (wid * 16 + ml) * 64 +
                      (((col16 >> 1) ^ (ml & 7)) * 8 + (col16 & 1) * 4)) =
                make_uint2(lo, hi);
        }

#pragma unroll
        for (int ks = 0; ks < 2; ks++) {
            short8 pf, vf[4];
            {
                const int c = (ks * 4 + quad) ^ (col16 & 7);
                pf = *(const short8*)(QP + (wid * 16 + col16) * 64 + c * 8);
            }
#pragma unroll
            for (int dt = 0; dt < 4; dt++) {
                const int d = dt * 16 + col16;
                const int c = (ks * 4 + quad) ^ (d & 7);
                vf[dt] = *(const short8*)(&VTs[cur][d * 64 + c * 8]);
            }
#pragma unroll
            for (int dt = 0; dt < 4; dt++)
                O[dt] = __builtin_amdgcn_mfma_f32_16x16x32_bf16(
                    pf, vf[dt], O[dt], 0, 0, 0);
        }
    }

    // row-sum reduction over the 16 col16 lanes (once)
#pragma unroll
    for (int r = 0; r < 4; r++) {
#pragma unroll
        for (int o2 = 1; o2 < 16; o2 <<= 1)
            lrun[r] += __shfl_xor(lrun[r], o2);
    }

    // O epilogue: b64 pos-layout (pos = col16*4 + dt), then gather to ctx
    const int b = bh >> 4, h = bh & 15;
#pragma unroll
    for (int r = 0; r < 4; r++) {
        const int ml = quad * 4 + r;
        const float inv = 1.0f / lrun[r];
        const u32 lo = pack2t(O[0][r] * inv, O[1][r] * inv);
        const u32 hi = pack2t(O[2][r] * inv, O[3][r] * inv);
        *(uint2*)(QP + (wid * 16 + ml) * 64 +
                  (((col16 >> 1) ^ (ml & 7)) * 8 + (col16 & 1) * 4)) =
            make_uint2(lo, hi);
    }
#pragma unroll
    for (int j = 0; j < 2; j++) {
        const int gg  = j * 64 + lane;      // 128 chunks: 16 rows x 8 d-chunks
        const int sl = gg >> 3;
        const int cir = gg & 7;
        u32 wv[4];
#pragma unroll
        for (int hw = 0; hw < 4; hw++) {
            const int d0 = cir * 8 + hw * 2;
            const int p0 = ((d0 & 15) << 2) | (d0 >> 4);
            const int d1 = d0 + 1;
            const int p1 = ((d1 & 15) << 2) | (d1 >> 4);
            const u16 v0 = QP[(wid * 16 + sl) * 64 + ((p0 >> 3) ^ (sl & 7)) * 8 + (p0 & 7)];
            const u16 v1 = QP[(wid * 16 + sl) * 64 + ((p1 >> 3) ^ (sl & 7)) * 8 + (p1 & 7)];
            wv[hw] = (u32)v0 | ((u32)v1 << 16);
        }
        const size_t rowbase =
            ((size_t)b * S_LEN + qBase + wid * 16 + sl) * EMB + h * 64;
        *(uint4*)(ctx + rowbase + cir * 8) = make_uint4(wv[0], wv[1], wv[2], wv[3]);
    }
}

// ---------------------------------------------------------------------------
// Kernel C: out(f32) = ctx * Wo^T. R16: 64x64 tiles, grid (64, 16) = 1024
// blocks = 4/CU (was 2/CU). LDS 16 KB. Wave owns 16 m-rows x 64 n.
// ---------------------------------------------------------------------------
__global__ __launch_bounds__(256) void proj_kernel(
    const u16* __restrict__ X, const u16* __restrict__ W, float* __restrict__ out)
{
    __shared__ __align__(16) u16 smem[8192];   // As 64x64 + Bs 64x64
    u16* As = smem;
    u16* Bs = smem + 64 * 64;

    const int tid   = threadIdx.x;
    const int lane  = tid & 63;
    const int wid   = tid >> 6;          // 0..3: m-row slice [wid*16, +16)
    const int col16 = lane & 15;
    const int quad  = lane >> 4;

    const int m0 = blockIdx.x * 64;
    const int n0 = blockIdx.y * 64;

    f32x4 acc[4];   // [nt] (operand-swapped: lane m = col16, n = quad*4+r)
    const f32x4 zero4 = {0.f, 0.f, 0.f, 0.f};
#pragma unroll
    for (int i = 0; i < 4; i++) acc[i] = zero4;

    const int drow = tid >> 3;
    const int dpos = tid & 7;
    const u16* Ag = X + (size_t)m0 * EMB;
    const u16* Bg = W + (size_t)n0 * EMB;

    for (int k0 = 0; k0 < EMB; k0 += 64) {
        __syncthreads();
#pragma unroll
        for (int j = 0; j < 2; j++) {
            const int rl = j * 32 + drow;
            const int cg = dpos ^ (rl & 7);
            lds_dma16(Ag + (size_t)rl * EMB + k0 + cg * 8,
                      As + (j * 32 + wid * 8) * 64);
        }
#pragma unroll
        for (int j = 0; j < 2; j++) {
            const int rl = j * 32 + drow;
            const int cg = dpos ^ (rl & 7);
            lds_dma16(Bg + (size_t)rl * EMB + k0 + cg * 8,
                      Bs + (j * 32 + wid * 8) * 64);
        }
        __syncthreads();

        short8 af[2], bf[4][2];
        {
            const int r = wid * 16 + col16;
#pragma unroll
            for (int ks = 0; ks < 2; ks++) {
                const int p = (ks * 4 + quad) ^ (r & 7);
                af[ks] = *(const short8*)(As + r * 64 + p * 8);
            }
        }
#pragma unroll
        for (int nt = 0; nt < 4; nt++) {
            const int r = nt * 16 + col16;
#pragma unroll
            for (int ks = 0; ks < 2; ks++) {
                const int p = (ks * 4 + quad) ^ (r & 7);
                bf[nt][ks] = *(const short8*)(Bs + r * 64 + p * 8);
            }
        }
#pragma unroll
        for (int ks = 0; ks < 2; ks++)
#pragma unroll
            for (int nt = 0; nt < 4; nt++)
                acc[nt] = __builtin_amdgcn_mfma_f32_16x16x32_bf16(
                    bf[nt][ks], af[ks], acc[nt], 0, 0, 0);
    }

#pragma unroll
    for (int nt = 0; nt < 4; nt++) {
        const int m_g = m0 + wid * 16 + col16;
        const int n_g = n0 + nt * 16 + quad * 4;
        *(f32x4*)(out + (size_t)m_g * EMB + n_g) = acc[nt];
    }
}

// ---------------------------------------------------------------------------
extern "C" void kernel_launch(void* const* d_in, const int* in_sizes, int n_in,
                              void* d_out, int out_size, void* d_ws, size_t ws_size,
                              hipStream_t stream)
{
    const float* x  = (const float*)d_in[0];
    const float* Wq = (const float*)d_in[1];
    const float* Wk = (const float*)d_in[2];
    const float* Wv = (const float*)d_in[3];
    const float* Wo = (const float*)d_in[4];

    u16* ws = (u16*)d_ws;
    u16* xb  = ws;
    u16* wb  = ws + 4194304;            // wq,wk,wv contiguous
    u16* wob = ws + 7340032;
    u16* q   = ws + 8388608;
    u16* k   = ws + 12582912;
    u16* v   = ws + 16777216;           // V^T [B,H,D,S], tau-ordered
    u16* ctx = ws + 20971520;
    float2* tab = (float2*)(ws + 25165824);   // 2048x32 float2 = 512 KB

    cast_kernel<<<dim3(2048, 6), 256, 0, stream>>>(x, Wq, Wk, Wv, Wo, ws, tab);
    qkv_rope_kernel<<<dim3(64, 24), 256, 0, stream>>>(xb, wb, tab, q, k, v);
    attn_kernel<<<dim3(32, 32), 256, 0, stream>>>(q, k, v, ctx);
    proj_kernel<<<dim3(64, 16), 256, 0, stream>>>(ctx, wob, (float*)d_out);
}